// Round 6
// baseline (314.959 us; speedup 1.0000x reference)
//
#include <hip/hip_runtime.h>
#include <hip/hip_bf16.h>

#define EMBED 768
#define DIMQ  800
#define INC   1024
#define NPIX  1024

typedef __bf16 bf16_t;
typedef __bf16 bf16x8 __attribute__((ext_vector_type(8)));
typedef float  f32x4  __attribute__((ext_vector_type(4)));

#define GLD_LDS(gp, lp) __builtin_amdgcn_global_load_lds( \
    (const __attribute__((address_space(1))) void*)(gp),  \
    (__attribute__((address_space(3))) void*)(lp), 16, 0, 0)

// ---------------- K0: x transpose->bf16 (oct-permuted) + cw convert (oct-permuted) + q0 ----------------
// xT[b][m][k] with k-octet slot = oct ^ (m&7) within each 64k group; cw same with (n&7).
__global__ __launch_bounds__(256)
void k_prep(const float* __restrict__ x, bf16_t* __restrict__ xT,
            const float* __restrict__ w, bf16_t* __restrict__ cw,
            const float* __restrict__ qkv_w, const float* __restrict__ qkv_b,
            const float* __restrict__ cls, const float* __restrict__ gender,
            float* __restrict__ q0b) {
    __shared__ __align__(16) float tile[64 * 64];   // fp32, XOR-quad swizzled
    const int bi = blockIdx.x;
    const int t  = threadIdx.x;
    if (bi < 8192) {
        // ---- transpose one (b, 64k, 64m) tile ----
        const int b  = bi >> 8;
        const int k0 = ((bi >> 4) & 15) * 64;
        const int m0 = (bi & 15) * 64;
        // stage 1: float4 global reads -> swizzled LDS (conflict-free b128)
        {
            const int kl = t >> 4;          // 0..15
            const int mq = t & 15;          // m-quad
#pragma unroll
            for (int r = 0; r < 4; ++r) {
                const int k = r * 16 + kl;
                f32x4 v = *(const f32x4*)(x + ((size_t)(b * 1024 + k0 + k) * 1024) + m0 + mq * 4);
                const int f = ((k >> 3) + (k & 7)) & 15;
                *(f32x4*)&tile[k * 64 + ((mq ^ f) & 15) * 4] = v;
            }
        }
        __syncthreads();
        // stage 2: transposed column reads (<=2-way), pack bf16x8, coalesced global write
        {
            const int j    = t & 7;         // oct
            const int mrow = t >> 3;        // 0..31
#pragma unroll
            for (int rep = 0; rep < 2; ++rep) {
                const int m = mrow + rep * 32;
                bf16x8 pk;
#pragma unroll
                for (int i = 0; i < 8; ++i) {
                    const int k = j * 8 + i;
                    const int f = ((k >> 3) + (k & 7)) & 15;
                    pk[i] = (bf16_t)tile[k * 64 + (((m >> 2) ^ f) & 15) * 4 + (m & 3)];
                }
                const int slot = j ^ (m & 7);
                *(bf16x8*)(xT + ((size_t)(b * 1024 + m0 + m) * 1024) + k0 + slot * 8) = pk;
            }
        }
    } else if (bi < 8392) {
        // ---- q0b[b*800+i] = (Wq t0[b] + bq)[i] ----
        const int wv = t >> 6, tl = t & 63;
        const int i = (bi - 8192) * 4 + wv;           // 0..799
        const float* row = qkv_w + (size_t)i * DIMQ;
        float ps = 0.f;
        for (int j = tl; j < EMBED; j += 64) ps += row[j] * cls[j];
#pragma unroll
        for (int off = 1; off < 64; off <<= 1) ps += __shfl_xor(ps, off, 64);
        if (tl < 32) {
            float g = 0.f;
#pragma unroll
            for (int j = 0; j < 32; ++j) g += row[EMBED + j] * gender[tl * 32 + j];
            q0b[tl * DIMQ + i] = ps + g + qkv_b[i];
        }
    } else {
        // ---- cw convert, oct slot = j ^ (n&7) ----
        const int i = (bi - 8392) * 256 + t;          // dst flat index
        const int n = i >> 10, k = i & 1023;
        const int s = (k >> 3) & 7;
        const int src_k = (k & ~63) | (((s ^ (n & 7)) & 7) << 3) | (k & 7);
        cw[i] = (bf16_t)w[(size_t)n * 1024 + src_k];
    }
}

// ---------------- K1: u[b][j] = ln_g[j] * sum_o Wk[o][j] q0[b][o], all b per block ----------------
// grid = 24 (j-chunks of 32), block = 1024 = 32 j x 32 b; wk read once (2.45 MB total)
__global__ __launch_bounds__(1024)
void k_u(const float* __restrict__ qkv_w, const float* __restrict__ q0b,
         const float* __restrict__ ln_g, float* __restrict__ u) {
    __shared__ float wk_s[160 * 32];
    __shared__ float q0_s[160 * 33];
    const int t  = threadIdx.x;
    const int j0 = blockIdx.x * 32;
    const int jj = t >> 5, b = t & 31;
    const float* wk = qkv_w + (size_t)DIMQ * DIMQ;
    float acc0 = 0.f, acc1 = 0.f;
    for (int c = 0; c < 5; ++c) {
        const int o0 = c * 160;
        __syncthreads();
#pragma unroll
        for (int i = 0; i < 5; ++i) {
            const int idx = i * 1024 + t;             // 0..5119
            const int o  = idx >> 5, jl = idx & 31;
            wk_s[o * 32 + jl] = wk[(size_t)(o0 + o) * DIMQ + j0 + jl];
            const int b2 = idx / 160, o2 = idx % 160;
            q0_s[o2 * 33 + b2] = q0b[b2 * DIMQ + o0 + o2];
        }
        __syncthreads();
#pragma unroll 8
        for (int o = 0; o < 160; o += 2) {
            acc0 += wk_s[o * 32 + jj]       * q0_s[o * 33 + b];
            acc1 += wk_s[(o + 1) * 32 + jj] * q0_s[(o + 1) * 33 + b];
        }
    }
    u[b * EMBED + j0 + jj] = (acc0 + acc1) * ln_g[j0 + jj];
}

// ---------------- K2: 128x128xK1024 GEMM tile + column reduction ----------------
__global__ __launch_bounds__(256, 3)
void k_main(const bf16_t* __restrict__ xT, const bf16_t* __restrict__ cw,
            const float* __restrict__ conv_b, const float* __restrict__ u,
            float* __restrict__ partial) {
    __shared__ __align__(1024) unsigned char smem[32768 + 3072];
    // A: 128 rows x 128 B @0 ; B: same @16384 ; part: 2x128x3 f32 @32768

    const int tid = threadIdx.x;
    // XCD swizzle: x8 = bi&7 -> XCD; sibling nt's consecutive on same XCD
    const int bi = blockIdx.x;
    const int x8 = bi & 7;
    const int s  = bi >> 3;
    const int nt = s % 6;
    const int mt = (s / 6) * 8 + x8;        // 0..255
    const int b  = mt >> 3;
    const int gm = mt * 128;                // global pixel row
    const int gn = nt * 128;                // global out-channel

    const int wv = tid >> 6;
    const int l  = tid & 63;
    const int lr = l >> 3;                  // row-in-8 for staging
    const int lc = l & 7;                   // oct slot for staging

    const int lane = l;
    const int col  = lane & 15;
    const int quad = lane >> 4;
    const int wm   = (wv >> 1) * 64;
    const int wn   = (wv & 1) * 64;

    bf16_t* A = (bf16_t*)smem;
    bf16_t* B = (bf16_t*)(smem + 16384);

    f32x4 C[4][4] = {};

    for (int kt = 0; kt < 16; ++kt) {
        const int ko = kt * 64;
        // ---- stage A+B via async DMA, linear lane mapping (swizzle pre-baked) ----
#pragma unroll
        for (int p = 0; p < 4; ++p) {
            const int r = p * 32 + wv * 8 + lr;
            GLD_LDS(xT + (size_t)(gm + r) * 1024 + ko + lc * 8, A + (p * 32 + wv * 8) * 64);
            GLD_LDS(cw + (size_t)(gn + r) * 1024 + ko + lc * 8, B + (p * 32 + wv * 8) * 64);
        }
        __syncthreads();
        // ---- 2 ks x 16 MFMA ----
#pragma unroll
        for (int ks = 0; ks < 2; ++ks) {
            bf16x8 af[4], bg[4];
#pragma unroll
            for (int mi = 0; mi < 4; ++mi) {
                const int r  = wm + mi * 16 + col;
                const int ph = (ks * 4 + quad) ^ (r & 7);
                af[mi] = *(const bf16x8*)(A + r * 64 + ph * 8);
            }
#pragma unroll
            for (int ni = 0; ni < 4; ++ni) {
                const int r  = wn + ni * 16 + col;
                const int ph = (ks * 4 + quad) ^ (r & 7);
                bg[ni] = *(const bf16x8*)(B + r * 64 + ph * 8);
            }
#pragma unroll
            for (int mi = 0; mi < 4; ++mi)
#pragma unroll
                for (int ni = 0; ni < 4; ++ni)
                    C[mi][ni] = __builtin_amdgcn_mfma_f32_16x16x32_bf16(af[mi], bg[ni], C[mi][ni], 0, 0, 0);
        }
        __syncthreads();
    }

    // ---- epilogue: fold 128 cols -> per-pixel (s1,s2,s3) partials ----
    float cb[4], uv[4];
#pragma unroll
    for (int ni = 0; ni < 4; ++ni) {
        const int og = gn + wn + ni * 16 + col;
        cb[ni] = conv_b[og];
        uv[ni] = u[b * EMBED + og];
    }
    float* part = (float*)(smem + 32768);   // [2 n-halves][128 rows][3]
#pragma unroll
    for (int mi = 0; mi < 4; ++mi)
#pragma unroll
        for (int r = 0; r < 4; ++r) {
            float a = 0.f, sq = 0.f, d = 0.f;
#pragma unroll
            for (int ni = 0; ni < 4; ++ni) {
                float v = C[mi][ni][r] + cb[ni];
                a += v; sq += v * v; d += v * uv[ni];
            }
#pragma unroll
            for (int off = 1; off < 16; off <<= 1) {
                a  += __shfl_xor(a, off, 64);
                sq += __shfl_xor(sq, off, 64);
                d  += __shfl_xor(d, off, 64);
            }
            if (col == 0) {
                const int row = wm + mi * 16 + quad * 4 + r;
                float* pp = part + ((wv & 1) * 128 + row) * 3;
                pp[0] = a; pp[1] = sq; pp[2] = d;
            }
        }
    __syncthreads();
    if (tid < 128) {
        const float* p0 = part + tid * 3;
        const float* p1 = part + (128 + tid) * 3;
        const size_t pix = (size_t)gm + tid;
        partial[(size_t)(0 * 6 + nt) * 32768 + pix] = p0[0] + p1[0];
        partial[(size_t)(1 * 6 + nt) * 32768 + pix] = p0[1] + p1[1];
        partial[(size_t)(2 * 6 + nt) * 32768 + pix] = p0[2] + p1[2];
    }
}

// ---------------- K3: combine partials -> scores -> softmax ----------------
__global__ __launch_bounds__(1024)
void k_final(const float* __restrict__ partial, const float* __restrict__ u,
             float* __restrict__ out) {
    __shared__ float red[16];
    __shared__ float bc[3];
    const int b = blockIdx.x, t = threadIdx.x;
    const int lane = t & 63, wid = t >> 6;

    float pu = (t < EMBED) ? u[b * EMBED + t] : 0.f;
#pragma unroll
    for (int off = 1; off < 64; off <<= 1) pu += __shfl_xor(pu, off, 64);
    if (lane == 0) red[wid] = pu;
    __syncthreads();
    if (t == 0) { float s = 0.f; for (int i = 0; i < 16; ++i) s += red[i]; bc[0] = s; }
    __syncthreads();
    const float Su = bc[0];

    const size_t m = (size_t)b * 1024 + t;
    float S1 = 0.f, S2 = 0.f, S3 = 0.f;
#pragma unroll
    for (int nt = 0; nt < 6; ++nt) {
        S1 += partial[(size_t)(0 * 6 + nt) * 32768 + m];
        S2 += partial[(size_t)(1 * 6 + nt) * 32768 + m];
        S3 += partial[(size_t)(2 * 6 + nt) * 32768 + m];
    }
    const float mu  = S1 * (1.f / 768.f);
    const float var = S2 * (1.f / 768.f) - mu * mu;
    const float sc  = 0.035355339059327376f * (S3 - mu * Su) * rsqrtf(var + 1e-5f);

    float mx = sc;
#pragma unroll
    for (int off = 1; off < 64; off <<= 1) mx = fmaxf(mx, __shfl_xor(mx, off, 64));
    if (lane == 0) red[wid] = mx;
    __syncthreads();
    if (t == 0) { float mm = -1e30f; for (int i = 0; i < 16; ++i) mm = fmaxf(mm, red[i]); bc[1] = mm; }
    __syncthreads();
    const float e = __expf(sc - bc[1]);
    float ss = e;
#pragma unroll
    for (int off = 1; off < 64; off <<= 1) ss += __shfl_xor(ss, off, 64);
    __syncthreads();
    if (lane == 0) red[wid] = ss;
    __syncthreads();
    if (t == 0) { float s = 0.f; for (int i = 0; i < 16; ++i) s += red[i]; bc[2] = s; }
    __syncthreads();
    out[m] = e / bc[2];
}

extern "C" void kernel_launch(void* const* d_in, const int* in_sizes, int n_in,
                              void* d_out, int out_size, void* d_ws, size_t ws_size,
                              hipStream_t stream) {
    const float* x      = (const float*)d_in[0];
    const float* gender = (const float*)d_in[1];
    const float* conv_w = (const float*)d_in[2];
    const float* conv_b = (const float*)d_in[3];
    const float* ln_g   = (const float*)d_in[4];
    // d_in[5] = ln_b : drops out of softmax
    const float* cls    = (const float*)d_in[6];
    const float* qkv_w  = (const float*)d_in[7];
    const float* qkv_b  = (const float*)d_in[8];
    float* out = (float*)d_out;

    char* ws = (char*)d_ws;
    bf16_t* cw      = (bf16_t*)ws;                 //  1,572,864 B
    float*  q0b     = (float*)(ws + 1572864);      //    102,400 B
    float*  u       = (float*)(ws + 1675264);      //     98,304 B
    float*  partial = (float*)(ws + 1773568);      //  2,359,296 B
    bf16_t* xT      = (bf16_t*)(ws + 4132864);     // 67,108,864 B (end ~71.2 MB)

    hipLaunchKernelGGL(k_prep,  dim3(11464), dim3(256),  0, stream,
                       x, xT, conv_w, cw, qkv_w, qkv_b, cls, gender, q0b);
    hipLaunchKernelGGL(k_u,     dim3(24),    dim3(1024), 0, stream, qkv_w, q0b, ln_g, u);
    hipLaunchKernelGGL(k_main,  dim3(1536),  dim3(256),  0, stream, xT, cw, conv_b, u, partial);
    hipLaunchKernelGGL(k_final, dim3(32),    dim3(1024), 0, stream, partial, u, out);
}